// Round 1
// baseline (209.488 us; speedup 1.0000x reference)
//
#include <hip/hip_runtime.h>

// Truncated signature, depth=3, C=8, B=512, L=8192.
// Kernel 1: per-(sample,chunk) signature via sequential Chen steps, one wave per chunk.
//   - lane (a,b) = (lane>>3, lane&7) owns S2[a][b] and S3[a][b][0..7].
//   - Abel-summed level-3 update so the k-operand p[k][t] is wave-uniform (scalar loads).
//   - per-lane dx[a], dx[b] from LDS-staged increments (conflict-free pattern).
// Kernel 2: per-sample in-order Chen combine of the G chunk signatures.

constexpr int B_ = 512;
constexpr int C_ = 8;
constexpr int L_ = 8192;
constexpr int NINC = L_ - 1;      // 8191 increments
constexpr int SIGDIM = 584;       // 8 + 64 + 512
constexpr int TILE = 128;         // staged steps per LDS tile

__global__ __launch_bounds__(256, 8)
void sig_chunks_kernel(const float* __restrict__ path, float* __restrict__ csig,
                       int G, int CPC) {
  __shared__ float lds[4 * TILE * C_];   // 16 KB: 4 waves x 128 steps x 8 ch
  const int wid  = __builtin_amdgcn_readfirstlane((int)(threadIdx.x >> 6));
  const int lane = (int)(threadIdx.x & 63);
  const int ia = lane >> 3;   // 'a'
  const int ib = lane & 7;    // 'b'
  const int wglob = __builtin_amdgcn_readfirstlane((int)blockIdx.x) * 4 + wid;
  const int samp = wglob / G;
  const int g    = wglob - samp * G;
  const int ts = g * CPC;
  const int te = (ts + CPC < NINC) ? (ts + CPC) : NINC;  // exclusive end of increments
  const float* pbase = path + (size_t)samp * (C_ * L_);
  float* ldsw = lds + wid * (TILE * C_);

  // staging mapping: channel = lane&7, time-row = lane>>3 (+8i)  -> conflict-free LDS writes
  const int s_c = lane & 7;
  const int s_t = lane >> 3;
  const float* srow = pbase + s_c * L_;

  float S3[8];
#pragma unroll
  for (int k = 0; k < 8; ++k) S3[k] = 0.f;
  float S2 = 0.f, s1a = 0.f, coefprev = 0.f;

  const int ntiles = (CPC + TILE - 1) / TILE;  // identical for every wave in grid
  for (int tt = 0; tt < ntiles; ++tt) {
    const int t0 = ts + tt * TILE;
    const int rem = te - t0;
    const int cnt = (rem < TILE) ? rem : TILE;   // >=1 always (CPC % TILE != 1)

    // ---- stage increments dx[t][c] for t in [0,cnt) ----
#pragma unroll
    for (int i = 0; i < TILE / 8; ++i) {
      const int t = s_t + 8 * i;
      if (t < cnt) {
        const float pl = srow[t0 + t];
        const float pr = srow[t0 + t + 1];
        ldsw[t * C_ + s_c] = pr - pl;
      }
    }
    __syncthreads();

    // ---- compute over this tile in blocks of 8 steps ----
    const int nb = (cnt + 7) >> 3;
    for (int blk = 0; blk < nb; ++blk) {
      const int u0loc = blk * 8;
      const int u0 = t0 + u0loc;           // global increment index
      const int mrem = te - u0;
      const int m = (mrem < 8) ? mrem : 8;
      float d[8];
      if (m == 8) {
        // phase 1: per-lane scalar recurrences
#pragma unroll
        for (int u = 0; u < 8; ++u) {
          const int tl = u0loc + u;
          const float dxa = ldsw[tl * C_ + ia];
          const float dxb = ldsw[tl * C_ + ib];
          const float t1 = __builtin_fmaf(dxa, (1.f / 3.f), s1a);
          const float coef = __builtin_fmaf(dxb, 0.5f * t1, S2);     // uses old S2
          S2 = __builtin_fmaf(dxb, __builtin_fmaf(dxa, 0.5f, s1a), S2);
          s1a += dxa;
          d[u] = coefprev - coef;
          coefprev = coef;
        }
        // phase 2: S3[k] += sum_u d[u] * p[k][u0+u]  (p uniform -> scalar loads)
#pragma unroll
        for (int k = 0; k < 8; ++k) {
          const float* pk = pbase + k * L_ + u0;
#pragma unroll
          for (int u = 0; u < 8; ++u)
            S3[k] = __builtin_fmaf(d[u], pk[u], S3[k]);
        }
      } else {
#pragma unroll
        for (int u = 0; u < 8; ++u) {
          if (u < m) {
            const int tl = u0loc + u;
            const float dxa = ldsw[tl * C_ + ia];
            const float dxb = ldsw[tl * C_ + ib];
            const float t1 = __builtin_fmaf(dxa, (1.f / 3.f), s1a);
            const float coef = __builtin_fmaf(dxb, 0.5f * t1, S2);
            S2 = __builtin_fmaf(dxb, __builtin_fmaf(dxa, 0.5f, s1a), S2);
            s1a += dxa;
            d[u] = coefprev - coef;
            coefprev = coef;
          } else {
            d[u] = 0.f;
          }
        }
#pragma unroll
        for (int k = 0; k < 8; ++k) {
          const float* pk = pbase + k * L_ + u0;
#pragma unroll
          for (int u = 0; u < 8; ++u)
            if (u < m) S3[k] = __builtin_fmaf(d[u], pk[u], S3[k]);
        }
      }
    }
    __syncthreads();   // protect LDS WAR before next tile's staging
  }

  // Abel boundary: + coef_{te-1} * p[k][te]
#pragma unroll
  for (int k = 0; k < 8; ++k)
    S3[k] = __builtin_fmaf(coefprev, pbase[k * L_ + te], S3[k]);

  float* cs = csig + ((size_t)samp * G + g) * SIGDIM;
  if (ib == 0) cs[ia] = s1a;
  cs[8 + lane] = S2;
#pragma unroll
  for (int k = 0; k < 8; ++k) cs[72 + lane * 8 + k] = S3[k];
}

__global__ __launch_bounds__(256)
void sig_combine_kernel(const float* __restrict__ csig, float* __restrict__ out, int G) {
  const int wid  = __builtin_amdgcn_readfirstlane((int)(threadIdx.x >> 6));
  const int lane = (int)(threadIdx.x & 63);
  const int ia = lane >> 3, ib = lane & 7;
  const int samp = __builtin_amdgcn_readfirstlane((int)blockIdx.x) * 4 + wid;
  const float* base = csig + (size_t)samp * G * SIGDIM;

  float R1a = base[ia];
  float R2  = base[8 + lane];
  float R3[8];
#pragma unroll
  for (int k = 0; k < 8; ++k) R3[k] = base[72 + lane * 8 + k];

  for (int g = 1; g < G; ++g) {
    const float* T = base + g * SIGDIM;
    float sT1[8];
#pragma unroll
    for (int k = 0; k < 8; ++k) sT1[k] = T[k];          // uniform -> scalar
    const float T1a  = T[ia];
    const float T1b  = T[ib];
    const float T2ab = T[8 + lane];
    float T2b[8], T3v[8];
#pragma unroll
    for (int k = 0; k < 8; ++k) T2b[k] = T[8 + ib * 8 + k];
#pragma unroll
    for (int k = 0; k < 8; ++k) T3v[k] = T[72 + lane * 8 + k];
    const float R1o = R1a, R2o = R2;
#pragma unroll
    for (int k = 0; k < 8; ++k)
      R3[k] += T3v[k] + R1o * T2b[k] + R2o * sT1[k];
    R2  += T2ab + R1o * T1b;
    R1a += T1a;
  }

  float* o = out + (size_t)samp * SIGDIM;
  if (ib == 0) o[ia] = R1a;
  o[8 + lane] = R2;
#pragma unroll
  for (int k = 0; k < 8; ++k) o[72 + lane * 8 + k] = R3[k];
}

extern "C" void kernel_launch(void* const* d_in, const int* in_sizes, int n_in,
                              void* d_out, int out_size, void* d_ws, size_t ws_size,
                              hipStream_t stream) {
  (void)in_sizes; (void)n_in; (void)out_size;
  const float* path = (const float*)d_in[0];
  float* out = (float*)d_out;
  float* ws  = (float*)d_ws;

  int G = 16;
  while (G > 1 && (size_t)B_ * G * SIGDIM * sizeof(float) > ws_size) G >>= 1;
  const int CPC = (NINC + G - 1) / G;   // increments per chunk

  sig_chunks_kernel<<<dim3(B_ * G / 4), dim3(256), 0, stream>>>(path, ws, G, CPC);
  sig_combine_kernel<<<dim3(B_ / 4), dim3(256), 0, stream>>>(ws, out, G);
}

// Round 2
// 136.270 us; speedup vs baseline: 1.5373x; 1.5373x over previous
//
#include <hip/hip_runtime.h>

// Truncated signature, depth=3, C=8, B=512, L=8192.
// Kernel 1: one wave per (sample, chunk); sequential Chen steps over the chunk.
//   lane (a,b)=(lane>>3, lane&7) owns S2[a][b], S3[a][b][0..7].
//   Level-3 via Abel summation: S3[k] += sum_u (coef_{u-1}-coef_u) * p[k][u] + boundary.
//   All per-step operands from LDS:
//     - increments dx in [c][t] layout (stride 68 -> conflict-free b128 reads)
//     - raw path p in [t][c] layout (uniform broadcast b128 reads)
//   Path read from HBM exactly once, coalesced float4.
// Kernel 2: per-sample in-order Chen combine of the G chunk signatures.

constexpr int B_ = 512;
constexpr int C_ = 8;
constexpr int L_ = 8192;
constexpr int NINC = L_ - 1;      // 8191 increments
constexpr int SIGDIM = 584;       // 8 + 64 + 512
constexpr int TILE = 64;          // steps per LDS tile
constexpr int DSTR = 68;          // dx row stride (floats): 68%32=4 -> 4-bank groups; 272B, 16B-aligned

__global__ __launch_bounds__(256, 8)
void sig_chunks_kernel(const float* __restrict__ path, float* __restrict__ csig,
                       int G, int CPC) {
  __shared__ __align__(16) float lds_p[4][TILE * C_];   // raw p, [t][c]   (2 KB/wave)
  __shared__ __align__(16) float lds_d[4][C_ * DSTR];   // dx,    [c][t]   (2.2 KB/wave)
  const int wid  = __builtin_amdgcn_readfirstlane((int)(threadIdx.x >> 6));
  const int lane = (int)(threadIdx.x & 63);
  const int ia = lane >> 3;   // 'a' (also staging channel)
  const int ib = lane & 7;    // 'b' (also staging position)
  const int wglob = __builtin_amdgcn_readfirstlane((int)blockIdx.x) * 4 + wid;
  const int samp = wglob / G;
  const int g    = wglob - samp * G;
  const int ts = g * CPC;
  const int te = (ts + CPC < NINC) ? (ts + CPC) : NINC;   // exclusive end
  const float* pbase = path + (size_t)samp * (C_ * L_);
  float* lp = lds_p[wid];
  float* ld = lds_d[wid];

  const int sc = ia;                 // staging channel
  const int si = ib;                 // staging position (4 consecutive t per float4)
  const float* prow = pbase + sc * L_;
  const int grp = lane & ~7;         // base lane of this channel group

  float S3[8];
#pragma unroll
  for (int k = 0; k < 8; ++k) S3[k] = 0.f;
  float S2 = 0.f, s1a = 0.f, coefprev = 0.f;

  const int ntiles = (CPC + TILE - 1) / TILE;   // uniform across grid
  for (int tt = 0; tt < ntiles; ++tt) {
    const int t0 = ts + tt * TILE;
    const int rem = te - t0;
    const int cnt = (rem < TILE) ? rem : TILE;   // >= 1 always

    // ---- stage: coalesced float4 loads, write raw p [t][c] and dx [c][t] ----
    const float4 v0 = *(const float4*)(prow + t0 + si * 4);
    const float4 v1 = *(const float4*)(prow + t0 + 32 + si * 4);
    float bnd = 0.f;
    if (t0 + TILE < L_) bnd = prow[t0 + TILE];

    lp[(si * 4 + 0) * C_ + sc] = v0.x;
    lp[(si * 4 + 1) * C_ + sc] = v0.y;
    lp[(si * 4 + 2) * C_ + sc] = v0.z;
    lp[(si * 4 + 3) * C_ + sc] = v0.w;
    lp[(32 + si * 4 + 0) * C_ + sc] = v1.x;
    lp[(32 + si * 4 + 1) * C_ + sc] = v1.y;
    lp[(32 + si * 4 + 2) * C_ + sc] = v1.z;
    lp[(32 + si * 4 + 3) * C_ + sc] = v1.w;

    // neighbor values for the last diff of each float4
    const float sA = __shfl(v0.x, lane + 1);
    const float sB = __shfl(v1.x, grp);
    const float sC = __shfl(v1.x, lane + 1);
    const float n0 = (si == 7) ? sB : sA;
    const float n1 = (si == 7) ? bnd : sC;
    float4 d0, d1;
    d0.x = v0.y - v0.x; d0.y = v0.z - v0.y; d0.z = v0.w - v0.z; d0.w = n0 - v0.w;
    d1.x = v1.y - v1.x; d1.y = v1.z - v1.y; d1.z = v1.w - v1.z; d1.w = n1 - v1.w;
    *(float4*)(ld + sc * DSTR + si * 4) = d0;
    *(float4*)(ld + sc * DSTR + 32 + si * 4) = d1;
    __syncthreads();

    // ---- compute: 8-step blocks ----
    const int nb = (cnt + 7) >> 3;
    for (int blk = 0; blk < nb; ++blk) {
      const int u0loc = blk * 8;
      const int mrem = te - (t0 + u0loc);
      const int m = (mrem < 8) ? mrem : 8;

      const float4 a0 = *(const float4*)(ld + ia * DSTR + u0loc);
      const float4 a1 = *(const float4*)(ld + ia * DSTR + u0loc + 4);
      const float4 b0 = *(const float4*)(ld + ib * DSTR + u0loc);
      const float4 b1 = *(const float4*)(ld + ib * DSTR + u0loc + 4);
      float da[8] = {a0.x, a0.y, a0.z, a0.w, a1.x, a1.y, a1.z, a1.w};
      float db[8] = {b0.x, b0.y, b0.z, b0.w, b1.x, b1.y, b1.z, b1.w};
      float d[8];

      if (m == 8) {
#pragma unroll
        for (int u = 0; u < 8; ++u) {
          const float hb = 0.5f * db[u];
          const float t1 = __builtin_fmaf(da[u], (1.f / 3.f), s1a);
          const float coef = __builtin_fmaf(hb, t1, S2);           // old S2
          S2 = __builtin_fmaf(hb, __builtin_fmaf(2.f, s1a, da[u]), S2);
          s1a += da[u];
          d[u] = coefprev - coef;
          coefprev = coef;
        }
      } else {
#pragma unroll
        for (int u = 0; u < 8; ++u) {
          if (u < m) {
            const float hb = 0.5f * db[u];
            const float t1 = __builtin_fmaf(da[u], (1.f / 3.f), s1a);
            const float coef = __builtin_fmaf(hb, t1, S2);
            S2 = __builtin_fmaf(hb, __builtin_fmaf(2.f, s1a, da[u]), S2);
            s1a += da[u];
            d[u] = coefprev - coef;
            coefprev = coef;
          } else {
            d[u] = 0.f;   // phase 2 fma is then a no-op (LDS holds finite data)
          }
        }
      }

      // phase 2: S3[k] += d[u] * p[k][u]  (p uniform broadcast from LDS)
#pragma unroll
      for (int u = 0; u < 8; ++u) {
        const float4 pA = *(const float4*)(lp + (u0loc + u) * C_);
        const float4 pB = *(const float4*)(lp + (u0loc + u) * C_ + 4);
        S3[0] = __builtin_fmaf(d[u], pA.x, S3[0]);
        S3[1] = __builtin_fmaf(d[u], pA.y, S3[1]);
        S3[2] = __builtin_fmaf(d[u], pA.z, S3[2]);
        S3[3] = __builtin_fmaf(d[u], pA.w, S3[3]);
        S3[4] = __builtin_fmaf(d[u], pB.x, S3[4]);
        S3[5] = __builtin_fmaf(d[u], pB.y, S3[5]);
        S3[6] = __builtin_fmaf(d[u], pB.z, S3[6]);
        S3[7] = __builtin_fmaf(d[u], pB.w, S3[7]);
      }
    }
    __syncthreads();   // protect LDS WAR before next tile's staging
  }

  // Abel boundary: + coef_{te-1} * p[k][te]  (te <= 8191, in-bounds)
#pragma unroll
  for (int k = 0; k < 8; ++k)
    S3[k] = __builtin_fmaf(coefprev, pbase[k * L_ + te], S3[k]);

  float* cs = csig + ((size_t)samp * G + g) * SIGDIM;
  if (ib == 0) cs[ia] = s1a;
  cs[8 + lane] = S2;
#pragma unroll
  for (int k = 0; k < 8; ++k) cs[72 + lane * 8 + k] = S3[k];
}

__global__ __launch_bounds__(256)
void sig_combine_kernel(const float* __restrict__ csig, float* __restrict__ out, int G) {
  const int wid  = __builtin_amdgcn_readfirstlane((int)(threadIdx.x >> 6));
  const int lane = (int)(threadIdx.x & 63);
  const int ia = lane >> 3, ib = lane & 7;
  const int samp = __builtin_amdgcn_readfirstlane((int)blockIdx.x) * 4 + wid;
  const float* base = csig + (size_t)samp * G * SIGDIM;

  float R1a = base[ia];
  float R2  = base[8 + lane];
  float R3[8];
#pragma unroll
  for (int k = 0; k < 8; ++k) R3[k] = base[72 + lane * 8 + k];

  for (int g = 1; g < G; ++g) {
    const float* T = base + g * SIGDIM;
    float sT1[8];
#pragma unroll
    for (int k = 0; k < 8; ++k) sT1[k] = T[k];
    const float T1a  = T[ia];
    const float T1b  = T[ib];
    const float T2ab = T[8 + lane];
    float T2b[8], T3v[8];
#pragma unroll
    for (int k = 0; k < 8; ++k) T2b[k] = T[8 + ib * 8 + k];
#pragma unroll
    for (int k = 0; k < 8; ++k) T3v[k] = T[72 + lane * 8 + k];
    const float R1o = R1a, R2o = R2;
#pragma unroll
    for (int k = 0; k < 8; ++k)
      R3[k] += T3v[k] + R1o * T2b[k] + R2o * sT1[k];
    R2  += T2ab + R1o * T1b;
    R1a += T1a;
  }

  float* o = out + (size_t)samp * SIGDIM;
  if (ib == 0) o[ia] = R1a;
  o[8 + lane] = R2;
#pragma unroll
  for (int k = 0; k < 8; ++k) o[72 + lane * 8 + k] = R3[k];
}

extern "C" void kernel_launch(void* const* d_in, const int* in_sizes, int n_in,
                              void* d_out, int out_size, void* d_ws, size_t ws_size,
                              hipStream_t stream) {
  (void)in_sizes; (void)n_in; (void)out_size;
  const float* path = (const float*)d_in[0];
  float* out = (float*)d_out;
  float* ws  = (float*)d_ws;

  int G = 16;
  while (G > 1 && (size_t)B_ * G * SIGDIM * sizeof(float) > ws_size) G >>= 1;
  const int CPC = (NINC + G - 1) / G;   // increments per chunk

  sig_chunks_kernel<<<dim3(B_ * G / 4), dim3(256), 0, stream>>>(path, ws, G, CPC);
  sig_combine_kernel<<<dim3(B_ / 4), dim3(256), 0, stream>>>(ws, out, G);
}

// Round 3
// 133.265 us; speedup vs baseline: 1.5720x; 1.0225x over previous
//
#include <hip/hip_runtime.h>

// Truncated signature, depth=3, C=8, B=512, L=8192.
// Kernel 1: one wave per (sample, chunk); sequential Chen steps over the chunk.
//   lane (a,b)=(lane>>3, lane&7) owns S2[a][b], S3[a][b][0..7].
//   Direct form: S3[k] += coef * dx[k][u], coef = S2 + S1[a]*db/2 + da*db/6.
//   dx staged in LDS in BOTH layouts (per-wave private, NO barriers):
//     Bc [c][t] stride 68          -> per-lane da/db b128 reads (broadcast groups)
//     A  [t][c] split 4+4 columns  -> uniform b128 reads; halves offset 264 floats
//                                     (bank +8) so scalar transpose writes are 4-way max
//   Path read from HBM once, coalesced float4, prefetched one tile ahead into regs.
// Kernel 2: per-sample in-order Chen combine of the G chunk signatures.

constexpr int B_ = 512;
constexpr int C_ = 8;
constexpr int L_ = 8192;
constexpr int NINC = L_ - 1;      // 8191 increments
constexpr int SIGDIM = 584;       // 8 + 64 + 512
constexpr int TILE = 64;          // steps per LDS tile
constexpr int BSTR = 68;          // Bc row stride (floats): 68%32=4 spreads rows
constexpr int AHOFF = 264;        // A high-half offset (floats): %32=8, 16B-aligned
constexpr int AWSZ = 520;         // A floats per wave (264 + 256)
constexpr int BWSZ = C_ * BSTR;   // 544

__global__ __launch_bounds__(256, 8)
void sig_chunks_kernel(const float* __restrict__ path, float* __restrict__ csig,
                       int G, int CPC) {
  __shared__ __align__(16) float As[4][AWSZ];
  __shared__ __align__(16) float Bs[4][BWSZ];
  const int wid  = __builtin_amdgcn_readfirstlane((int)(threadIdx.x >> 6));
  const int lane = (int)(threadIdx.x & 63);
  const int ia = lane >> 3;   // 'a' == staging channel sc
  const int ib = lane & 7;    // 'b' == staging position si
  const int wglob = __builtin_amdgcn_readfirstlane((int)blockIdx.x) * 4 + wid;
  const int samp = wglob / G;
  const int g    = wglob - samp * G;
  const int ts = g * CPC;
  const int te = (ts + CPC < NINC) ? (ts + CPC) : NINC;   // exclusive end
  const float* pbase = path + (size_t)samp * (C_ * L_);
  float* as_ = As[wid];
  float* bs  = Bs[wid];

  const int si = ib;                       // staging position (4 consecutive t)
  const float* prow = pbase + ia * L_;     // staging channel row
  const int grp = lane & ~7;               // si=0 lane of this channel group
  // scalar-transpose write base: column (ia&3) of low/high half
  float* aw = as_ + (ia >> 2) * AHOFF + (ia & 3);

  float S3[8];
#pragma unroll
  for (int k = 0; k < 8; ++k) S3[k] = 0.f;
  float S2 = 0.f, s1a = 0.f;

  const int ntiles = (CPC + TILE - 1) / TILE;   // uniform across grid (=8)

  // prologue: prefetch tile 0 + boundary
  float4 r0 = *(const float4*)(prow + ts + si * 4);
  float4 r1 = *(const float4*)(prow + ts + 32 + si * 4);
  float bnd = prow[ts + TILE];              // ts+64 <= 7744 < 8192 always

  for (int tt = 0; tt < ntiles; ++tt) {
    const int t0 = ts + tt * TILE;
    const int cnt_ = te - t0;
    const int cnt = (cnt_ < TILE) ? cnt_ : TILE;

    // ---- stage tile tt from regs (diffs + dual-layout LDS writes) ----
    {
      const float4 v0 = r0, v1 = r1;
      const float sA = __shfl(v0.x, lane + 1);
      const float sB = __shfl(v1.x, grp);
      const float sC = __shfl(v1.x, lane + 1);
      const float n0 = (si == 7) ? sB : sA;
      const float n1 = (si == 7) ? bnd : sC;
      float4 d0, d1;
      d0.x = v0.y - v0.x; d0.y = v0.z - v0.y; d0.z = v0.w - v0.z; d0.w = n0 - v0.w;
      d1.x = v1.y - v1.x; d1.y = v1.z - v1.y; d1.z = v1.w - v1.z; d1.w = n1 - v1.w;
      *(float4*)(bs + ia * BSTR + si * 4) = d0;
      *(float4*)(bs + ia * BSTR + 32 + si * 4) = d1;
      const int tl = si * 4;
      aw[(tl + 0) * 4] = d0.x;
      aw[(tl + 1) * 4] = d0.y;
      aw[(tl + 2) * 4] = d0.z;
      aw[(tl + 3) * 4] = d0.w;
      aw[(32 + tl + 0) * 4] = d1.x;
      aw[(32 + tl + 1) * 4] = d1.y;
      aw[(32 + tl + 2) * 4] = d1.z;
      aw[(32 + tl + 3) * 4] = d1.w;
    }

    // ---- prefetch tile tt+1 (latency hidden under compute below) ----
    if (tt + 1 < ntiles) {
      const int t1g = t0 + TILE;
      r0 = *(const float4*)(prow + t1g + si * 4);
      r1 = *(const float4*)(prow + t1g + 32 + si * 4);
      const int bn = t1g + TILE;
      bnd = (bn < L_) ? prow[bn] : 0.f;
    }

    // ---- compute tile tt ----
    if (cnt == TILE) {
#pragma unroll
      for (int blk = 0; blk < 8; ++blk) {
        const int u0 = blk * 8;
        const float4 a0 = *(const float4*)(bs + ia * BSTR + u0);
        const float4 a1 = *(const float4*)(bs + ia * BSTR + u0 + 4);
        const float4 b0 = *(const float4*)(bs + ib * BSTR + u0);
        const float4 b1 = *(const float4*)(bs + ib * BSTR + u0 + 4);
        const float da[8] = {a0.x, a0.y, a0.z, a0.w, a1.x, a1.y, a1.z, a1.w};
        const float db[8] = {b0.x, b0.y, b0.z, b0.w, b1.x, b1.y, b1.z, b1.w};
#pragma unroll
        for (int u = 0; u < 8; ++u) {
          const float4 pA = *(const float4*)(as_ + (u0 + u) * 4);
          const float4 pB = *(const float4*)(as_ + AHOFF + (u0 + u) * 4);
          const float hb = 0.5f * db[u];
          const float w  = __builtin_fmaf(da[u], (1.f / 3.f), s1a);
          const float coef = __builtin_fmaf(hb, w, S2);
          const float z  = __builtin_fmaf(da[u], (2.f / 3.f), s1a);
          S2 = __builtin_fmaf(hb, z, coef);
          s1a += da[u];
          S3[0] = __builtin_fmaf(coef, pA.x, S3[0]);
          S3[1] = __builtin_fmaf(coef, pA.y, S3[1]);
          S3[2] = __builtin_fmaf(coef, pA.z, S3[2]);
          S3[3] = __builtin_fmaf(coef, pA.w, S3[3]);
          S3[4] = __builtin_fmaf(coef, pB.x, S3[4]);
          S3[5] = __builtin_fmaf(coef, pB.y, S3[5]);
          S3[6] = __builtin_fmaf(coef, pB.z, S3[6]);
          S3[7] = __builtin_fmaf(coef, pB.w, S3[7]);
        }
      }
    } else {
      // tail tile (only last chunk's last tile, cnt=63): guarded, cold path
      for (int blk = 0; blk < 8; ++blk) {
        const int u0 = blk * 8;
        int m = cnt - u0; if (m > 8) m = 8;
        if (m <= 0) break;
        const float4 a0 = *(const float4*)(bs + ia * BSTR + u0);
        const float4 a1 = *(const float4*)(bs + ia * BSTR + u0 + 4);
        const float4 b0 = *(const float4*)(bs + ib * BSTR + u0);
        const float4 b1 = *(const float4*)(bs + ib * BSTR + u0 + 4);
        const float da[8] = {a0.x, a0.y, a0.z, a0.w, a1.x, a1.y, a1.z, a1.w};
        const float db[8] = {b0.x, b0.y, b0.z, b0.w, b1.x, b1.y, b1.z, b1.w};
#pragma unroll
        for (int u = 0; u < 8; ++u) {
          if (u < m) {
            const float4 pA = *(const float4*)(as_ + (u0 + u) * 4);
            const float4 pB = *(const float4*)(as_ + AHOFF + (u0 + u) * 4);
            const float hb = 0.5f * db[u];
            const float w  = __builtin_fmaf(da[u], (1.f / 3.f), s1a);
            const float coef = __builtin_fmaf(hb, w, S2);
            const float z  = __builtin_fmaf(da[u], (2.f / 3.f), s1a);
            S2 = __builtin_fmaf(hb, z, coef);
            s1a += da[u];
            S3[0] = __builtin_fmaf(coef, pA.x, S3[0]);
            S3[1] = __builtin_fmaf(coef, pA.y, S3[1]);
            S3[2] = __builtin_fmaf(coef, pA.z, S3[2]);
            S3[3] = __builtin_fmaf(coef, pA.w, S3[3]);
            S3[4] = __builtin_fmaf(coef, pB.x, S3[4]);
            S3[5] = __builtin_fmaf(coef, pB.y, S3[5]);
            S3[6] = __builtin_fmaf(coef, pB.z, S3[6]);
            S3[7] = __builtin_fmaf(coef, pB.w, S3[7]);
          }
        }
      }
    }
  }

  float* cs = csig + ((size_t)samp * G + g) * SIGDIM;
  if (ib == 0) cs[ia] = s1a;
  cs[8 + lane] = S2;
#pragma unroll
  for (int k = 0; k < 8; ++k) cs[72 + lane * 8 + k] = S3[k];
}

__global__ __launch_bounds__(256)
void sig_combine_kernel(const float* __restrict__ csig, float* __restrict__ out, int G) {
  const int wid  = __builtin_amdgcn_readfirstlane((int)(threadIdx.x >> 6));
  const int lane = (int)(threadIdx.x & 63);
  const int ia = lane >> 3, ib = lane & 7;
  const int samp = __builtin_amdgcn_readfirstlane((int)blockIdx.x) * 4 + wid;
  const float* base = csig + (size_t)samp * G * SIGDIM;

  float R1a = base[ia];
  float R2  = base[8 + lane];
  float R3[8];
#pragma unroll
  for (int k = 0; k < 8; ++k) R3[k] = base[72 + lane * 8 + k];

  for (int g = 1; g < G; ++g) {
    const float* T = base + g * SIGDIM;
    float sT1[8];
#pragma unroll
    for (int k = 0; k < 8; ++k) sT1[k] = T[k];
    const float T1a  = T[ia];
    const float T1b  = T[ib];
    const float T2ab = T[8 + lane];
    float T2b[8], T3v[8];
#pragma unroll
    for (int k = 0; k < 8; ++k) T2b[k] = T[8 + ib * 8 + k];
#pragma unroll
    for (int k = 0; k < 8; ++k) T3v[k] = T[72 + lane * 8 + k];
    const float R1o = R1a, R2o = R2;
#pragma unroll
    for (int k = 0; k < 8; ++k)
      R3[k] += T3v[k] + R1o * T2b[k] + R2o * sT1[k];
    R2  += T2ab + R1o * T1b;
    R1a += T1a;
  }

  float* o = out + (size_t)samp * SIGDIM;
  if (ib == 0) o[ia] = R1a;
  o[8 + lane] = R2;
#pragma unroll
  for (int k = 0; k < 8; ++k) o[72 + lane * 8 + k] = R3[k];
}

extern "C" void kernel_launch(void* const* d_in, const int* in_sizes, int n_in,
                              void* d_out, int out_size, void* d_ws, size_t ws_size,
                              hipStream_t stream) {
  (void)in_sizes; (void)n_in; (void)out_size;
  const float* path = (const float*)d_in[0];
  float* out = (float*)d_out;
  float* ws  = (float*)d_ws;

  int G = 16;
  while (G > 1 && (size_t)B_ * G * SIGDIM * sizeof(float) > ws_size) G >>= 1;
  const int CPC = (NINC + G - 1) / G;   // increments per chunk

  sig_chunks_kernel<<<dim3(B_ * G / 4), dim3(256), 0, stream>>>(path, ws, G, CPC);
  sig_combine_kernel<<<dim3(B_ / 4), dim3(256), 0, stream>>>(ws, out, G);
}

// Round 4
// 129.698 us; speedup vs baseline: 1.6152x; 1.0275x over previous
//
#include <hip/hip_runtime.h>

// Truncated signature, depth=3, C=8, B=512, L=8192.
// Kernel 1: one wave per (sample, chunk); sequential Chen steps over the chunk.
//   lane (a,b)=(lane>>3, lane&7) owns S2[a][b], S3[a][b][0..7].
//   All LDS arrays hold dx/2:
//     B  [c][t] stride 68            -> per-lane da2/db2 b128 reads (octet broadcast)
//     A  [t][c] split 4+4 columns    -> uniform b128 broadcast reads (halves at +AHOFF)
//   Recurrence (true values): w=s1a+da/3, z=s1a+2da/3, coef=S2+db2*w, S2+=db2*(w+z),
//   s1a+=da; S3 accumulates coef*dx/2 -> x2 at epilogue.
// Kernel 2: per-sample in-order Chen combine of the G chunk signatures.

constexpr int B_ = 512;
constexpr int C_ = 8;
constexpr int L_ = 8192;
constexpr int NINC = L_ - 1;      // 8191 increments
constexpr int SIGDIM = 584;       // 8 + 64 + 512
constexpr int TILE = 64;          // steps per LDS tile
constexpr int BSTR = 68;          // B row stride (floats)
constexpr int AHOFF = 264;        // A high-half offset (floats), 16B-aligned
constexpr int AWSZ = 520;
constexpr int BWSZ = C_ * BSTR;   // 544

#define SIG_STEP(DAV, DBV, PLO, PHI)                          \
  do {                                                        \
    const float w_ = __builtin_fmaf((DAV), (2.f/3.f), s1a);   \
    const float z_ = __builtin_fmaf((DAV), (4.f/3.f), s1a);   \
    const float cf = __builtin_fmaf((DBV), w_, S2);           \
    S2  = __builtin_fmaf((DBV), z_, cf);                      \
    s1a = __builtin_fmaf((DAV), 2.f, s1a);                    \
    S3[0] = __builtin_fmaf(cf, (PLO).x, S3[0]);               \
    S3[1] = __builtin_fmaf(cf, (PLO).y, S3[1]);               \
    S3[2] = __builtin_fmaf(cf, (PLO).z, S3[2]);               \
    S3[3] = __builtin_fmaf(cf, (PLO).w, S3[3]);               \
    S3[4] = __builtin_fmaf(cf, (PHI).x, S3[4]);               \
    S3[5] = __builtin_fmaf(cf, (PHI).y, S3[5]);               \
    S3[6] = __builtin_fmaf(cf, (PHI).z, S3[6]);               \
    S3[7] = __builtin_fmaf(cf, (PHI).w, S3[7]);               \
  } while (0)

__global__ __launch_bounds__(256, 8)
void sig_chunks_kernel(const float* __restrict__ path, float* __restrict__ csig,
                       int G, int CPC) {
  __shared__ __align__(16) float As[4][AWSZ];
  __shared__ __align__(16) float Bs[4][BWSZ];
  const int wid  = __builtin_amdgcn_readfirstlane((int)(threadIdx.x >> 6));
  const int lane = (int)(threadIdx.x & 63);
  const int ia = lane >> 3;   // 'a' == staging channel
  const int ib = lane & 7;    // 'b' == staging position
  const int wglob = __builtin_amdgcn_readfirstlane((int)blockIdx.x) * 4 + wid;
  const int samp = wglob / G;
  const int g    = wglob - samp * G;
  const int ts = g * CPC;
  const int te = (ts + CPC < NINC) ? (ts + CPC) : NINC;   // exclusive end
  const float* pbase = path + (size_t)samp * (C_ * L_);
  float* as_ = As[wid];
  float* bs  = Bs[wid];

  const int si = ib;
  const float* prow = pbase + ia * L_;
  const int grp = lane & ~7;
  float* aw = as_ + (ia >> 2) * AHOFF + (ia & 3);

  float S3[8];
#pragma unroll
  for (int k = 0; k < 8; ++k) S3[k] = 0.f;
  float S2 = 0.f, s1a = 0.f;

  const int ntiles = (CPC + TILE - 1) / TILE;   // uniform across grid

  // prologue: prefetch tile 0 + boundary
  float4 r0 = *(const float4*)(prow + ts + si * 4);
  float4 r1 = *(const float4*)(prow + ts + 32 + si * 4);
  float bnd = prow[ts + TILE];

  for (int tt = 0; tt < ntiles; ++tt) {
    const int t0 = ts + tt * TILE;
    const int cnt_ = te - t0;
    const int cnt = (cnt_ < TILE) ? cnt_ : TILE;

    // ---- stage tile tt from regs: halved diffs into both LDS layouts ----
    {
      const float4 v0 = r0, v1 = r1;
      const float sA = __shfl(v0.x, lane + 1);
      const float sB = __shfl(v1.x, grp);
      const float sC = __shfl(v1.x, lane + 1);
      const float n0 = (si == 7) ? sB : sA;
      const float n1 = (si == 7) ? bnd : sC;
      float4 d0, d1;
      d0.x = (v0.y - v0.x) * 0.5f;
      d0.y = (v0.z - v0.y) * 0.5f;
      d0.z = (v0.w - v0.z) * 0.5f;
      d0.w = (n0 - v0.w) * 0.5f;
      d1.x = (v1.y - v1.x) * 0.5f;
      d1.y = (v1.z - v1.y) * 0.5f;
      d1.z = (v1.w - v1.z) * 0.5f;
      d1.w = (n1 - v1.w) * 0.5f;
      *(float4*)(bs + ia * BSTR + si * 4) = d0;
      *(float4*)(bs + ia * BSTR + 32 + si * 4) = d1;
      const int tl = si * 4;
      aw[(tl + 0) * 4] = d0.x;
      aw[(tl + 1) * 4] = d0.y;
      aw[(tl + 2) * 4] = d0.z;
      aw[(tl + 3) * 4] = d0.w;
      aw[(32 + tl + 0) * 4] = d1.x;
      aw[(32 + tl + 1) * 4] = d1.y;
      aw[(32 + tl + 2) * 4] = d1.z;
      aw[(32 + tl + 3) * 4] = d1.w;
    }

    // ---- prefetch tile tt+1 ----
    if (tt + 1 < ntiles) {
      const int t1g = t0 + TILE;
      r0 = *(const float4*)(prow + t1g + si * 4);
      r1 = *(const float4*)(prow + t1g + 32 + si * 4);
      const int bn = t1g + TILE;
      bnd = (bn < L_) ? prow[bn] : 0.f;
    }

    // ---- compute tile tt ----
    if (cnt == TILE) {
#pragma unroll
      for (int blk = 0; blk < 8; ++blk) {
        const int u0 = blk * 8;
        const float4 a0 = *(const float4*)(bs + ia * BSTR + u0);
        const float4 a1 = *(const float4*)(bs + ia * BSTR + u0 + 4);
        const float4 b0 = *(const float4*)(bs + ib * BSTR + u0);
        const float4 b1 = *(const float4*)(bs + ib * BSTR + u0 + 4);
        // one-step-ahead rotation for the uniform row reads
        float4 P0 = *(const float4*)(as_ + u0 * 4);
        float4 P1 = *(const float4*)(as_ + AHOFF + u0 * 4);
        float4 Q0, Q1;
        Q0 = *(const float4*)(as_ + (u0 + 1) * 4);
        Q1 = *(const float4*)(as_ + AHOFF + (u0 + 1) * 4);
        SIG_STEP(a0.x, b0.x, P0, P1); P0 = Q0; P1 = Q1;
        Q0 = *(const float4*)(as_ + (u0 + 2) * 4);
        Q1 = *(const float4*)(as_ + AHOFF + (u0 + 2) * 4);
        SIG_STEP(a0.y, b0.y, P0, P1); P0 = Q0; P1 = Q1;
        Q0 = *(const float4*)(as_ + (u0 + 3) * 4);
        Q1 = *(const float4*)(as_ + AHOFF + (u0 + 3) * 4);
        SIG_STEP(a0.z, b0.z, P0, P1); P0 = Q0; P1 = Q1;
        Q0 = *(const float4*)(as_ + (u0 + 4) * 4);
        Q1 = *(const float4*)(as_ + AHOFF + (u0 + 4) * 4);
        SIG_STEP(a0.w, b0.w, P0, P1); P0 = Q0; P1 = Q1;
        Q0 = *(const float4*)(as_ + (u0 + 5) * 4);
        Q1 = *(const float4*)(as_ + AHOFF + (u0 + 5) * 4);
        SIG_STEP(a1.x, b1.x, P0, P1); P0 = Q0; P1 = Q1;
        Q0 = *(const float4*)(as_ + (u0 + 6) * 4);
        Q1 = *(const float4*)(as_ + AHOFF + (u0 + 6) * 4);
        SIG_STEP(a1.y, b1.y, P0, P1); P0 = Q0; P1 = Q1;
        Q0 = *(const float4*)(as_ + (u0 + 7) * 4);
        Q1 = *(const float4*)(as_ + AHOFF + (u0 + 7) * 4);
        SIG_STEP(a1.z, b1.z, P0, P1); P0 = Q0; P1 = Q1;
        SIG_STEP(a1.w, b1.w, P0, P1);
      }
    } else {
      // tail tile (only the last chunk's last tile), cold path
      for (int blk = 0; blk < 8; ++blk) {
        const int u0 = blk * 8;
        int m = cnt - u0; if (m > 8) m = 8;
        if (m <= 0) break;
        const float4 a0 = *(const float4*)(bs + ia * BSTR + u0);
        const float4 a1 = *(const float4*)(bs + ia * BSTR + u0 + 4);
        const float4 b0 = *(const float4*)(bs + ib * BSTR + u0);
        const float4 b1 = *(const float4*)(bs + ib * BSTR + u0 + 4);
        const float da[8] = {a0.x, a0.y, a0.z, a0.w, a1.x, a1.y, a1.z, a1.w};
        const float db[8] = {b0.x, b0.y, b0.z, b0.w, b1.x, b1.y, b1.z, b1.w};
#pragma unroll
        for (int u = 0; u < 8; ++u) {
          if (u < m) {
            const float4 PLO = *(const float4*)(as_ + (u0 + u) * 4);
            const float4 PHI = *(const float4*)(as_ + AHOFF + (u0 + u) * 4);
            SIG_STEP(da[u], db[u], PLO, PHI);
          }
        }
      }
    }
  }

  float* cs = csig + ((size_t)samp * G + g) * SIGDIM;
  if (ib == 0) cs[ia] = s1a;
  cs[8 + lane] = S2;
  float4 o0, o1;
  o0.x = 2.f * S3[0]; o0.y = 2.f * S3[1]; o0.z = 2.f * S3[2]; o0.w = 2.f * S3[3];
  o1.x = 2.f * S3[4]; o1.y = 2.f * S3[5]; o1.z = 2.f * S3[6]; o1.w = 2.f * S3[7];
  *(float4*)(cs + 72 + lane * 8)     = o0;
  *(float4*)(cs + 72 + lane * 8 + 4) = o1;
}

__global__ __launch_bounds__(256)
void sig_combine_kernel(const float* __restrict__ csig, float* __restrict__ out, int G) {
  const int wid  = __builtin_amdgcn_readfirstlane((int)(threadIdx.x >> 6));
  const int lane = (int)(threadIdx.x & 63);
  const int ia = lane >> 3, ib = lane & 7;
  const int samp = __builtin_amdgcn_readfirstlane((int)blockIdx.x) * 4 + wid;
  const float* base = csig + (size_t)samp * G * SIGDIM;

  float R1a = base[ia];
  float R2  = base[8 + lane];
  float R3[8];
#pragma unroll
  for (int k = 0; k < 8; ++k) R3[k] = base[72 + lane * 8 + k];

  for (int g = 1; g < G; ++g) {
    const float* T = base + g * SIGDIM;
    float sT1[8];
#pragma unroll
    for (int k = 0; k < 8; ++k) sT1[k] = T[k];
    const float T1a  = T[ia];
    const float T1b  = T[ib];
    const float T2ab = T[8 + lane];
    float T2b[8], T3v[8];
#pragma unroll
    for (int k = 0; k < 8; ++k) T2b[k] = T[8 + ib * 8 + k];
#pragma unroll
    for (int k = 0; k < 8; ++k) T3v[k] = T[72 + lane * 8 + k];
    const float R1o = R1a, R2o = R2;
#pragma unroll
    for (int k = 0; k < 8; ++k)
      R3[k] += T3v[k] + R1o * T2b[k] + R2o * sT1[k];
    R2  += T2ab + R1o * T1b;
    R1a += T1a;
  }

  float* o = out + (size_t)samp * SIGDIM;
  if (ib == 0) o[ia] = R1a;
  o[8 + lane] = R2;
#pragma unroll
  for (int k = 0; k < 8; ++k) o[72 + lane * 8 + k] = R3[k];
}

extern "C" void kernel_launch(void* const* d_in, const int* in_sizes, int n_in,
                              void* d_out, int out_size, void* d_ws, size_t ws_size,
                              hipStream_t stream) {
  (void)in_sizes; (void)n_in; (void)out_size;
  const float* path = (const float*)d_in[0];
  float* out = (float*)d_out;
  float* ws  = (float*)d_ws;

  int G = 16;
  while (G > 1 && (size_t)B_ * G * SIGDIM * sizeof(float) > ws_size) G >>= 1;
  const int CPC = (NINC + G - 1) / G;   // increments per chunk

  sig_chunks_kernel<<<dim3(B_ * G / 4), dim3(256), 0, stream>>>(path, ws, G, CPC);
  sig_combine_kernel<<<dim3(B_ / 4), dim3(256), 0, stream>>>(ws, out, G);
}